// Round 7
// baseline (126.808 us; speedup 1.0000x reference)
//
#include <hip/hip_runtime.h>

// CausalSelfAttention: B=4, T=2048, D=1024, DA=256, fp32 in/out.
// 4 launches: prep (convert + transposes + W upper-tri zero-fill) ->
// gemm_qk -> vt_scores (Vt GEMM || scores, independent) -> pv_fin.
// MFMA kernels: T4 counted-vmcnt double-buffer pipeline + T2 source-swizzled
// LDS (linear dest for global_load_lds, XOR slot on read).

typedef short bf16x8 __attribute__((ext_vector_type(8)));   // 8 bf16 in 4 VGPRs
typedef float f32x4  __attribute__((ext_vector_type(4)));
typedef unsigned int  u32x4 __attribute__((ext_vector_type(4)));
typedef unsigned short u16x4 __attribute__((ext_vector_type(4)));

static __device__ __forceinline__ unsigned short f2bf(float f) {
    union { float f; unsigned int u; } v; v.f = f;
    unsigned int u = v.u;
    return (unsigned short)((u + 0x7FFFu + ((u >> 16) & 1u)) >> 16);  // RNE
}
static __device__ __forceinline__ float bf2f(unsigned short h) {
    union { unsigned int u; float f; } v; v.u = ((unsigned int)h) << 16; return v.f;
}

// async global->LDS, 16B per lane; LDS dest must be wave-linear (lane*16).
#define GLL(g, l) __builtin_amdgcn_global_load_lds( \
    (const __attribute__((address_space(1))) void*)(g), \
    (__attribute__((address_space(3))) void*)(l), 16, 0, 0)

#define BAR() __builtin_amdgcn_s_barrier()
#define VM8() asm volatile("s_waitcnt vmcnt(8)" ::: "memory")
#define VM0() asm volatile("s_waitcnt vmcnt(0)" ::: "memory")

// ---- shared pipeline body: uses in-scope As,Bs,srow,scol,sw0,wr,wc,fr,acc ----

#define STAGE1(AB, LDA, BB, LDB, t, p) { \
    const unsigned short* Ap_ = (AB) + (size_t)(t) * 64; \
    const unsigned short* Bp_ = (BB) + (size_t)(t) * 64; \
    _Pragma("unroll") \
    for (int i_ = 0; i_ < 4; ++i_) { \
        GLL(Ap_ + (size_t)32 * i_ * (LDA), &As[p][srow + 32 * i_][scol]); \
        GLL(Bp_ + (size_t)32 * i_ * (LDB), &Bs[p][srow + 32 * i_][scol]); \
    } }

#define PIPE_MFMA(AB, LDA, BB, LDB, NT) { \
    STAGE1(AB, LDA, BB, LDB, 0, 0); \
    STAGE1(AB, LDA, BB, LDB, 1, 1); \
    for (int t = 0; t < (NT); ++t) { \
        int p = t & 1; \
        if (t + 1 < (NT)) VM8(); else VM0(); \
        BAR(); \
        _Pragma("unroll") \
        for (int ks = 0; ks < 64; ks += 32) { \
            int fo = ks ? (sw0 ^ 32) : sw0; \
            bf16x8 af[4], bfr[4]; \
            _Pragma("unroll") \
            for (int i = 0; i < 4; ++i) af[i]  = *(const bf16x8*)(&As[p][wr + 16 * i + fr][fo]); \
            _Pragma("unroll") \
            for (int j = 0; j < 4; ++j) bfr[j] = *(const bf16x8*)(&Bs[p][wc + 16 * j + fr][fo]); \
            _Pragma("unroll") \
            for (int i = 0; i < 4; ++i) \
            _Pragma("unroll") \
                for (int j = 0; j < 4; ++j) \
                    acc[i][j] = __builtin_amdgcn_mfma_f32_16x16x32_bf16(af[i], bfr[j], acc[i][j], 0, 0, 0); \
        } \
        BAR(); \
        if (t + 2 < (NT)) STAGE1(AB, LDA, BB, LDB, t + 2, p); \
    } }

#define TILE_IDS() \
    int tid = threadIdx.x; \
    int lane = tid & 63, wave = tid >> 6; \
    int wr = (wave >> 1) * 64, wc = (wave & 1) * 64; \
    int fr = lane & 15; \
    int srow = tid >> 3, scol = (tid & 7) * 8; \
    int scolg = (((tid & 7) ^ (srow & 7)) * 8); \
    int sw0 = (((lane >> 4) ^ (fr & 7)) * 8)

// ---------------- prep: x->bf16 + 3 weight transposes + W zero-fill ----------------

__global__ __launch_bounds__(256) void prep(
    const float* __restrict__ x, const float* __restrict__ Wq,
    const float* __restrict__ Wk, const float* __restrict__ Wv,
    unsigned short* __restrict__ x_bf, unsigned short* __restrict__ Wqk_t,
    unsigned short* __restrict__ Wv_t, float* __restrict__ Wout)
{
    int bid = blockIdx.x, tid = threadIdx.x;
    if (bid < 8192) {           // convert x: 8192*256 threads * 4 elems
        int i = bid * 256 + tid;
        f32x4 v = ((const f32x4*)x)[i];
        u16x4 o;
        o[0] = f2bf(v[0]); o[1] = f2bf(v[1]); o[2] = f2bf(v[2]); o[3] = f2bf(v[3]);
        ((u16x4*)x_bf)[i] = o;
        return;
    }
    if (bid >= 9728) {          // zero-fill fully-above-diagonal 128x128 W tiles
        int t = bid - 9728;     // 0..479
        int b = t / 120; t -= b * 120;
        int y = 0, rem = t;
        while (rem >= 15 - y) { rem -= 15 - y; ++y; }
        int xx = y + 1 + rem;
        float* base = Wout + (size_t)b * 2048 * 2048
                    + (size_t)(y * 128 + (tid >> 1)) * 2048 + xx * 128 + (tid & 1) * 64;
        f32x4 z = {};
#pragma unroll
        for (int i = 0; i < 16; ++i) ((f32x4*)base)[i] = z;
        return;
    }
    // transpose-convert W[K=1024][N] -> Wt[N][1024], scaled
    const float* W; unsigned short* Wt; int N, lb; float scale;
    if (bid < 8448)      { W = Wq; Wt = Wqk_t;              N = 256;  lb = bid - 8192; scale = 1.f / 16.f; }
    else if (bid < 8704) { W = Wk; Wt = Wqk_t + 256 * 1024; N = 256;  lb = bid - 8448; scale = 1.f; }
    else                 { W = Wv; Wt = Wv_t;               N = 1024; lb = bid - 8704; scale = 1.f; }
    int nb = N >> 5;
    int n0 = (lb % nb) * 32, k0 = (lb / nb) * 32;
    int tx = tid & 31, ty = tid >> 5;   // 32 x 8
    __shared__ float tile[32][33];
#pragma unroll
    for (int r = 0; r < 4; ++r)
        tile[ty + 8 * r][tx] = W[(size_t)(k0 + ty + 8 * r) * N + n0 + tx];
    __syncthreads();
#pragma unroll
    for (int r = 0; r < 4; ++r)
        Wt[(size_t)(n0 + ty + 8 * r) * 1024 + k0 + tx] = f2bf(tile[tx][ty + 8 * r] * scale);
}

// ---------------- gemm_qk: QK [8192 x 512] = x_bf @ Wqk_t^T ----------------

__global__ __launch_bounds__(256) void gemm_qk(
    const unsigned short* __restrict__ x_bf,
    const unsigned short* __restrict__ Wqk_t,
    unsigned short* __restrict__ QK_bf)
{
    int bid = blockIdx.x;
    int m0 = (bid >> 2) * 128, n0 = (bid & 3) * 128;
    __shared__ __align__(16) unsigned short As[2][128][64];
    __shared__ __align__(16) unsigned short Bs[2][128][64];
    TILE_IDS();
    f32x4 acc[4][4] = {};
    const unsigned short* Ab = x_bf + (size_t)(m0 + srow) * 1024 + scolg;
    const unsigned short* Bb = Wqk_t + (size_t)(n0 + srow) * 1024 + scolg;
    PIPE_MFMA(Ab, 1024, Bb, 1024, 16);
#pragma unroll
    for (int i = 0; i < 4; ++i)
#pragma unroll
        for (int j = 0; j < 4; ++j)
#pragma unroll
            for (int r = 0; r < 4; ++r)
                QK_bf[(size_t)(m0 + wr + 16 * i + (lane >> 4) * 4 + r) * 512
                      + n0 + wc + 16 * j + fr] = f2bf(acc[i][j][r]);
}

// ---------------- vt_scores: Vt GEMM (0..511) || scores (512..1055) ----------------

__global__ __launch_bounds__(256) void vt_scores(
    const unsigned short* __restrict__ x_bf,
    const unsigned short* __restrict__ Wv_t,
    const unsigned short* __restrict__ QK,
    unsigned short* __restrict__ Vt_bf,
    unsigned short* __restrict__ Ebf,
    float* __restrict__ partials)
{
    int bid = blockIdx.x;
    __shared__ __align__(16) unsigned short As[2][128][64];
    __shared__ __align__(16) unsigned short Bs[2][128][64];

    if (bid < 512) {
        // Vt [1024 x 8192] = Wv_t @ x_bf^T
        int m0 = (bid >> 6) * 128, n0 = (bid & 63) * 128;
        TILE_IDS();
        f32x4 acc[4][4] = {};
        const unsigned short* Ab = Wv_t + (size_t)(m0 + srow) * 1024 + scolg;
        const unsigned short* Bb = x_bf + (size_t)(n0 + srow) * 1024 + scolg;
        PIPE_MFMA(Ab, 1024, Bb, 1024, 16);
#pragma unroll
        for (int i = 0; i < 4; ++i)
#pragma unroll
            for (int j = 0; j < 4; ++j)
#pragma unroll
                for (int r = 0; r < 4; ++r)
                    Vt_bf[(size_t)(m0 + wr + 16 * i + (lane >> 4) * 4 + r) * 8192
                          + n0 + wc + 16 * j + fr] = f2bf(acc[i][j][r]);
        return;
    }

    // scores: E = exp(Q Kt^T) bf16 + partial row sums; live tiles only.
    int lin = bid - 512;                      // 0..543
    int swz = (lin & 7) * 68 + (lin >> 3);
    int b = swz / 136, t = swz - b * 136;
    int y = (int)floorf((sqrtf(8.f * (float)t + 1.f) - 1.f) * 0.5f);
    if ((y + 1) * (y + 2) / 2 <= t) ++y;
    if (y * (y + 1) / 2 > t) --y;
    int x = t - y * (y + 1) / 2;
    int m0 = y * 128, n0 = x * 128;

    const unsigned short* A  = QK + (size_t)b * 2048 * 512;
    const unsigned short* Bt = A + 256;
    unsigned short* Eb = Ebf + (size_t)b * 2048 * 2048;

    __shared__ float rowsum2[2][128];
    TILE_IDS();
    f32x4 acc[4][4] = {};
    const unsigned short* Ab = A  + (size_t)(m0 + srow) * 512 + scolg;
    const unsigned short* Bb = Bt + (size_t)(n0 + srow) * 512 + scolg;
    PIPE_MFMA(Ab, 512, Bb, 512, 4);

#pragma unroll
    for (int i = 0; i < 4; ++i)
#pragma unroll
        for (int r = 0; r < 4; ++r) {
            int q = m0 + wr + 16 * i + (lane >> 4) * 4 + r;
            float s = 0.f;
#pragma unroll
            for (int j = 0; j < 4; ++j) {
                int k = n0 + wc + 16 * j + fr;
                float e = (k <= q) ? __expf(acc[i][j][r]) : 0.f;
                Eb[(size_t)q * 2048 + k] = f2bf(e);
                s += e;
            }
            s += __shfl_xor(s, 1, 64); s += __shfl_xor(s, 2, 64);
            s += __shfl_xor(s, 4, 64); s += __shfl_xor(s, 8, 64);
            if (fr == 0) rowsum2[wave & 1][wr + 16 * i + (lane >> 4) * 4 + r] = s;
        }
    __syncthreads();
    if (tid < 128)
        partials[((size_t)b * 2048 + m0 + tid) * 16 + x] =
            rowsum2[0][tid] + rowsum2[1][tid];
}

// ---------------- pv_fin: PV GEMM (0..511) + W finalize live-only (512..2559) ----------------

__global__ __launch_bounds__(256) void pv_fin(
    const unsigned short* __restrict__ E, const unsigned short* __restrict__ Vt,
    const float* __restrict__ partials, float* __restrict__ O,
    float* __restrict__ W)
{
    int bid = blockIdx.x;
    __shared__ __align__(16) unsigned short As[2][128][64];
    __shared__ __align__(16) unsigned short Bs[2][128][64];
    __shared__ float invsh[128];

    if (bid < 512) {
        // PV: O = (E @ V) * inv, causal k-limit, XCD-balanced decode
        int j   = bid & 7;
        int idx = bid >> 3;
        int x   = idx & 7;
        int h   = idx >> 3;
        int b   = h >> 1;
        int y   = (h & 1) ? j : 15 - j;

        int m0 = y * 128, n0 = x * 128;
        const unsigned short* Pb = E + (size_t)b * 2048 * 2048;
        const unsigned short* Bt = Vt + (size_t)b * 2048;   // ldb = 8192
        float* Ob = O + (size_t)b * 2048 * 1024;
        int nt = (y + 1) * 2;

        TILE_IDS();
        f32x4 acc[4][4] = {};

        if (tid < 128) {
            const float* pp = partials + ((size_t)b * 2048 + m0 + tid) * 16;
            float s = 0.f;
            for (int i = 0; i <= y; ++i) s += pp[i];
            invsh[tid] = 1.f / s;
        }

        const unsigned short* Ab = Pb + (size_t)(m0 + srow) * 2048 + scolg;
        const unsigned short* Bb = Bt + (size_t)(n0 + srow) * 8192 + scolg;
        PIPE_MFMA(Ab, 2048, Bb, 8192, nt);
#pragma unroll
        for (int i = 0; i < 4; ++i)
#pragma unroll
            for (int r = 0; r < 4; ++r) {
                int rloc = wr + 16 * i + (lane >> 4) * 4 + r;
                float iv = invsh[rloc];
#pragma unroll
                for (int jj = 0; jj < 4; ++jj)
                    Ob[(size_t)(m0 + rloc) * 1024 + n0 + wc + 16 * jj + fr] = acc[i][jj][r] * iv;
            }
        return;
    }

    // finalize: 4 rows/block, one row/wave; writes only cols < tile_end
    // (above-tile zeros were written by prep).
    int tid = threadIdx.x;
    int wave = tid >> 6, lane = tid & 63;
    int r = (bid - 512) * 4 + wave;       // 0..8191
    int q = r & 2047;
    int tile_end = ((q >> 7) + 1) << 7;
    float p = (lane < 16 && lane <= (q >> 7)) ? partials[(size_t)r * 16 + lane] : 0.f;
    p += __shfl_xor(p, 1, 64); p += __shfl_xor(p, 2, 64);
    p += __shfl_xor(p, 4, 64); p += __shfl_xor(p, 8, 64);
    float iv = 1.f / __shfl(p, 0, 64);
    const unsigned short* er = E + (size_t)r * 2048;
    float* wrow = W + (size_t)r * 2048;
#pragma unroll
    for (int cc = 0; cc < 4; ++cc) {
        int c0 = lane * 8 + cc * 512;
        if (c0 >= tile_end) continue;
        f32x4 o0 = {}, o1 = {};
        if (c0 <= q) {   // masked entries within a live chunk are exact bf16 zeros
            bf16x8 e = *(const bf16x8*)(er + c0);
#pragma unroll
            for (int j = 0; j < 4; ++j) {
                o0[j] = bf2f((unsigned short)e[j]) * iv;
                o1[j] = bf2f((unsigned short)e[j + 4]) * iv;
            }
        }
        *((f32x4*)(wrow + c0)) = o0;
        *((f32x4*)(wrow + c0) + 1) = o1;
    }
}

// ---------------- launcher ----------------

extern "C" void kernel_launch(void* const* d_in, const int* in_sizes, int n_in,
                              void* d_out, int out_size, void* d_ws, size_t ws_size,
                              hipStream_t stream) {
    (void)in_sizes; (void)n_in; (void)out_size; (void)ws_size;
    const float* x  = (const float*)d_in[0];
    const float* Wq = (const float*)d_in[1];
    const float* Wk = (const float*)d_in[2];
    const float* Wv = (const float*)d_in[3];
    const int B = 4, T = 2048, D = 1024;
    const int M = B * T;  // 8192

    char* ws = (char*)d_ws;
    size_t off = 0;
    auto alloc = [&](size_t bytes) {
        void* p = ws + off; off += (bytes + 255) & ~(size_t)255; return p;
    };
    unsigned short* x_bf  = (unsigned short*)alloc((size_t)M * D * 2);
    unsigned short* Wqk_t = (unsigned short*)alloc((size_t)512 * D * 2);
    unsigned short* Wv_t  = (unsigned short*)alloc((size_t)D * D * 2);
    unsigned short* QK_bf = (unsigned short*)alloc((size_t)M * 512 * 2);
    unsigned short* Vt_bf = (unsigned short*)alloc((size_t)D * M * 2);
    unsigned short* E_bf  = (unsigned short*)alloc((size_t)M * T * 2);
    float*          parts = (float*)alloc((size_t)M * 16 * 4);

    float* outO = (float*)d_out;                       // [4][2048][1024]
    float* outW = (float*)d_out + (size_t)M * D;       // [4][2048][2048]

    // 1. prep: x->bf16 + weight transposes + above-diagonal W zero tiles
    prep<<<dim3(8192 + 256 + 256 + 1024 + 480), 256, 0, stream>>>(
        x, Wq, Wk, Wv, x_bf, Wqk_t, Wv_t, outW);

    // 2. QK GEMM (scores' only dependency)
    gemm_qk<<<dim3(256), 256, 0, stream>>>(x_bf, Wqk_t, QK_bf);

    // 3. Vt GEMM || scores (independent given QK)
    vt_scores<<<dim3(512 + 544), 256, 0, stream>>>(
        x_bf, Wv_t, QK_bf, Vt_bf, E_bf, parts);

    // 4. PV GEMM + W finalize (live region only)
    pv_fin<<<dim3(512 + 2048), 256, 0, stream>>>(E_bf, Vt_bf, parts, outO, outW);
}

// Round 8
// 116.449 us; speedup vs baseline: 1.0890x; 1.0890x over previous
//
#include <hip/hip_runtime.h>

// CausalSelfAttention: B=4, T=2048, D=1024, DA=256, fp32 in/out.
// 4 launches: prep (convert + transposes + W upper-tri zero-fill) ->
// qkvt (QK GEMM interleaved with Vt GEMM) -> scores (bf16 E + partials) ->
// pv_fin (PV GEMM with 2D-XCD-tiled decode + live-only W finalize).
// MFMA kernels: T4 counted-vmcnt double-buffer pipeline + T2 source-swizzled
// LDS (linear dest for global_load_lds, XOR slot on read).

typedef short bf16x8 __attribute__((ext_vector_type(8)));   // 8 bf16 in 4 VGPRs
typedef float f32x4  __attribute__((ext_vector_type(4)));
typedef unsigned int  u32x4 __attribute__((ext_vector_type(4)));
typedef unsigned short u16x4 __attribute__((ext_vector_type(4)));

static __device__ __forceinline__ unsigned short f2bf(float f) {
    union { float f; unsigned int u; } v; v.f = f;
    unsigned int u = v.u;
    return (unsigned short)((u + 0x7FFFu + ((u >> 16) & 1u)) >> 16);  // RNE
}
static __device__ __forceinline__ float bf2f(unsigned short h) {
    union { unsigned int u; float f; } v; v.u = ((unsigned int)h) << 16; return v.f;
}

// async global->LDS, 16B per lane; LDS dest must be wave-linear (lane*16).
#define GLL(g, l) __builtin_amdgcn_global_load_lds( \
    (const __attribute__((address_space(1))) void*)(g), \
    (__attribute__((address_space(3))) void*)(l), 16, 0, 0)

#define BAR() __builtin_amdgcn_s_barrier()
#define VM8() asm volatile("s_waitcnt vmcnt(8)" ::: "memory")
#define VM0() asm volatile("s_waitcnt vmcnt(0)" ::: "memory")

// ---- shared pipeline body: uses in-scope As,Bs,srow,scol,sw0,wr,wc,fr,acc ----

#define STAGE1(AB, LDA, BB, LDB, t, p) { \
    const unsigned short* Ap_ = (AB) + (size_t)(t) * 64; \
    const unsigned short* Bp_ = (BB) + (size_t)(t) * 64; \
    _Pragma("unroll") \
    for (int i_ = 0; i_ < 4; ++i_) { \
        GLL(Ap_ + (size_t)32 * i_ * (LDA), &As[p][srow + 32 * i_][scol]); \
        GLL(Bp_ + (size_t)32 * i_ * (LDB), &Bs[p][srow + 32 * i_][scol]); \
    } }

#define PIPE_MFMA(AB, LDA, BB, LDB, NT) { \
    STAGE1(AB, LDA, BB, LDB, 0, 0); \
    STAGE1(AB, LDA, BB, LDB, 1, 1); \
    for (int t = 0; t < (NT); ++t) { \
        int p = t & 1; \
        if (t + 1 < (NT)) VM8(); else VM0(); \
        BAR(); \
        _Pragma("unroll") \
        for (int ks = 0; ks < 64; ks += 32) { \
            int fo = ks ? (sw0 ^ 32) : sw0; \
            bf16x8 af[4], bfr[4]; \
            _Pragma("unroll") \
            for (int i = 0; i < 4; ++i) af[i]  = *(const bf16x8*)(&As[p][wr + 16 * i + fr][fo]); \
            _Pragma("unroll") \
            for (int j = 0; j < 4; ++j) bfr[j] = *(const bf16x8*)(&Bs[p][wc + 16 * j + fr][fo]); \
            _Pragma("unroll") \
            for (int i = 0; i < 4; ++i) \
            _Pragma("unroll") \
                for (int j = 0; j < 4; ++j) \
                    acc[i][j] = __builtin_amdgcn_mfma_f32_16x16x32_bf16(af[i], bfr[j], acc[i][j], 0, 0, 0); \
        } \
        BAR(); \
        if (t + 2 < (NT)) STAGE1(AB, LDA, BB, LDB, t + 2, p); \
    } }

#define TILE_IDS() \
    int tid = threadIdx.x; \
    int lane = tid & 63, wave = tid >> 6; \
    int wr = (wave >> 1) * 64, wc = (wave & 1) * 64; \
    int fr = lane & 15; \
    int srow = tid >> 3, scol = (tid & 7) * 8; \
    int scolg = (((tid & 7) ^ (srow & 7)) * 8); \
    int sw0 = (((lane >> 4) ^ (fr & 7)) * 8)

// y-quad member: balanced causal groups {G, 7-G, 8+G, 15-G}
static __device__ __forceinline__ int ymem(int G, int yi) {
    return (yi == 0) ? G : (yi == 1) ? 7 - G : (yi == 2) ? 8 + G : 15 - G;
}

// ---------------- prep: x->bf16 + weight transposes + W zero-fill ----------------

__global__ __launch_bounds__(256) void prep(
    const float* __restrict__ x, const float* __restrict__ Wq,
    const float* __restrict__ Wk, const float* __restrict__ Wv,
    unsigned short* __restrict__ x_bf, unsigned short* __restrict__ Wqk_t,
    unsigned short* __restrict__ Wv_t, float* __restrict__ Wout)
{
    int bid = blockIdx.x, tid = threadIdx.x;
    if (bid < 2048) {           // convert x, grid-strided: 4 f32x4 per thread
        const f32x4* src = (const f32x4*)x;
        u16x4* dst = (u16x4*)x_bf;
        int i = bid * 256 + tid;
#pragma unroll
        for (int s = 0; s < 4; ++s) {
            f32x4 v = src[i + s * 524288];
            u16x4 o;
            o[0] = f2bf(v[0]); o[1] = f2bf(v[1]); o[2] = f2bf(v[2]); o[3] = f2bf(v[3]);
            dst[i + s * 524288] = o;
        }
        return;
    }
    if (bid < 2528) {           // zero-fill fully-above-diagonal 128x128 W tiles
        int t = bid - 2048;     // 0..479
        int b = t / 120; t -= b * 120;
        int y = 0, rem = t;
        while (rem >= 15 - y) { rem -= 15 - y; ++y; }
        int xx = y + 1 + rem;
        float* base = Wout + (size_t)b * 2048 * 2048
                    + (size_t)(y * 128 + (tid >> 1)) * 2048 + xx * 128 + (tid & 1) * 64;
        f32x4 z = {};
#pragma unroll
        for (int i = 0; i < 16; ++i) ((f32x4*)base)[i] = z;
        return;
    }
    // transpose-convert W[K=1024][N] -> Wt[N][1024], scaled
    const float* W; unsigned short* Wt; int N, lb; float scale;
    if (bid < 2784)      { W = Wq; Wt = Wqk_t;              N = 256;  lb = bid - 2528; scale = 1.f / 16.f; }
    else if (bid < 3040) { W = Wk; Wt = Wqk_t + 256 * 1024; N = 256;  lb = bid - 2784; scale = 1.f; }
    else                 { W = Wv; Wt = Wv_t;               N = 1024; lb = bid - 3040; scale = 1.f; }
    int nb = N >> 5;
    int n0 = (lb % nb) * 32, k0 = (lb / nb) * 32;
    int tx = tid & 31, ty = tid >> 5;   // 32 x 8
    __shared__ float tile[32][33];
#pragma unroll
    for (int r = 0; r < 4; ++r)
        tile[ty + 8 * r][tx] = W[(size_t)(k0 + ty + 8 * r) * N + n0 + tx];
    __syncthreads();
#pragma unroll
    for (int r = 0; r < 4; ++r)
        Wt[(size_t)(n0 + ty + 8 * r) * 1024 + k0 + tx] = f2bf(tile[tx][ty + 8 * r] * scale);
}

// ---------------- qkvt: Vt GEMM + QK GEMM, mod-3 interleaved ----------------
// bid%3==2 -> QK tile bid/3 (256 tiles, [8192x512] = x_bf @ Wqk_t^T)
// else     -> Vt tile 2*(bid/3)+bid%3 (512 tiles, [1024x8192] = Wv_t @ x_bf^T)

__global__ __launch_bounds__(256) void gemm_qkvt(
    const unsigned short* __restrict__ x_bf,
    const unsigned short* __restrict__ Wqk_t,
    const unsigned short* __restrict__ Wv_t,
    unsigned short* __restrict__ QK_bf,
    unsigned short* __restrict__ Vt_bf)
{
    int bid = blockIdx.x;
    int g = bid / 3, r3 = bid - 3 * g;
    const unsigned short *A, *B; unsigned short* C; int ldc, m0, n0;
    if (r3 == 2) {
        A = x_bf; B = Wqk_t; C = QK_bf; ldc = 512;
        m0 = (g >> 2) * 128; n0 = (g & 3) * 128;
    } else {
        int v = 2 * g + r3;
        A = Wv_t; B = x_bf; C = Vt_bf; ldc = 8192;
        m0 = (v >> 6) * 128; n0 = (v & 63) * 128;
    }
    __shared__ __align__(16) unsigned short As[2][128][64];
    __shared__ __align__(16) unsigned short Bs[2][128][64];
    TILE_IDS();
    f32x4 acc[4][4] = {};
    const unsigned short* Ab = A + (size_t)(m0 + srow) * 1024 + scolg;
    const unsigned short* Bb = B + (size_t)(n0 + srow) * 1024 + scolg;
    PIPE_MFMA(Ab, 1024, Bb, 1024, 16);
#pragma unroll
    for (int i = 0; i < 4; ++i)
#pragma unroll
        for (int j = 0; j < 4; ++j)
#pragma unroll
            for (int r = 0; r < 4; ++r)
                C[(size_t)(m0 + wr + 16 * i + (lane >> 4) * 4 + r) * ldc
                  + n0 + wc + 16 * j + fr] = f2bf(acc[i][j][r]);
}

// ---------------- scores: E = exp(Q Kt^T) bf16 + partial row sums ----------------
// Live (causal) tiles only: 544 blocks, XCD-bijective swizzle (544 = 8*68).

__global__ __launch_bounds__(256) void scores_e(
    const unsigned short* __restrict__ QK, unsigned short* __restrict__ Ebf,
    float* __restrict__ partials)
{
    int lin = blockIdx.x;                     // 0..543
    int swz = (lin & 7) * 68 + (lin >> 3);
    int b = swz / 136, t = swz - b * 136;
    int y = (int)floorf((sqrtf(8.f * (float)t + 1.f) - 1.f) * 0.5f);
    if ((y + 1) * (y + 2) / 2 <= t) ++y;
    if (y * (y + 1) / 2 > t) --y;
    int x = t - y * (y + 1) / 2;
    int m0 = y * 128, n0 = x * 128;

    const unsigned short* A  = QK + (size_t)b * 2048 * 512;
    const unsigned short* Bt = A + 256;
    unsigned short* Eb = Ebf + (size_t)b * 2048 * 2048;

    __shared__ __align__(16) unsigned short As[2][128][64];
    __shared__ __align__(16) unsigned short Bs[2][128][64];
    __shared__ float rowsum2[2][128];
    TILE_IDS();
    f32x4 acc[4][4] = {};
    const unsigned short* Ab = A  + (size_t)(m0 + srow) * 512 + scolg;
    const unsigned short* Bb = Bt + (size_t)(n0 + srow) * 512 + scolg;
    PIPE_MFMA(Ab, 512, Bb, 512, 4);

#pragma unroll
    for (int i = 0; i < 4; ++i)
#pragma unroll
        for (int r = 0; r < 4; ++r) {
            int q = m0 + wr + 16 * i + (lane >> 4) * 4 + r;
            float s = 0.f;
#pragma unroll
            for (int j = 0; j < 4; ++j) {
                int k = n0 + wc + 16 * j + fr;
                float e = (k <= q) ? __expf(acc[i][j][r]) : 0.f;
                Eb[(size_t)q * 2048 + k] = f2bf(e);
                s += e;
            }
            s += __shfl_xor(s, 1, 64); s += __shfl_xor(s, 2, 64);
            s += __shfl_xor(s, 4, 64); s += __shfl_xor(s, 8, 64);
            if (fr == 0) rowsum2[wave & 1][wr + 16 * i + (lane >> 4) * 4 + r] = s;
        }
    __syncthreads();
    if (tid < 128)
        partials[((size_t)b * 2048 + m0 + tid) * 16 + x] =
            rowsum2[0][tid] + rowsum2[1][tid];
}

// ---------------- pv_fin: PV GEMM (0..511, 2D-XCD-tiled) + W finalize ----------------
// PV: XCD j = bid&7 owns x-group (j&1: 4 x-tiles) x balanced y-quad (G=j>>1);
// all 64 blocks/XCD co-resident -> Vt panel prefixes + E row panels stay in
// that XCD's L2. fin blocks use matching XCD-affine decode (E reuse from L2).

__global__ __launch_bounds__(256) void pv_fin(
    const unsigned short* __restrict__ E, const unsigned short* __restrict__ Vt,
    const float* __restrict__ partials, float* __restrict__ O,
    float* __restrict__ W)
{
    int bid = blockIdx.x;
    __shared__ __align__(16) unsigned short As[2][128][64];
    __shared__ __align__(16) unsigned short Bs[2][128][64];
    __shared__ float invsh[128];

    if (bid < 512) {
        int j = bid & 7, w = bid >> 3;        // XCD, within-XCD index
        int G = j >> 1, X = j & 1;
        int x  = X * 4 + (w >> 4);
        int y  = ymem(G, (w >> 2) & 3);
        int b  = w & 3;

        int m0 = y * 128, n0 = x * 128;
        const unsigned short* Pb = E + (size_t)b * 2048 * 2048;
        const unsigned short* Bt = Vt + (size_t)b * 2048;   // ldb = 8192
        float* Ob = O + (size_t)b * 2048 * 1024;
        int nt = (y + 1) * 2;

        TILE_IDS();
        f32x4 acc[4][4] = {};

        if (tid < 128) {
            const float* pp = partials + ((size_t)b * 2048 + m0 + tid) * 16;
            float s = 0.f;
            for (int i = 0; i <= y; ++i) s += pp[i];
            invsh[tid] = 1.f / s;
        }

        const unsigned short* Ab = Pb + (size_t)(m0 + srow) * 2048 + scolg;
        const unsigned short* Bb = Bt + (size_t)(n0 + srow) * 8192 + scolg;
        PIPE_MFMA(Ab, 2048, Bb, 8192, nt);
#pragma unroll
        for (int i = 0; i < 4; ++i)
#pragma unroll
            for (int r = 0; r < 4; ++r) {
                int rloc = wr + 16 * i + (lane >> 4) * 4 + r;
                float iv = invsh[rloc];
#pragma unroll
                for (int jj = 0; jj < 4; ++jj)
                    Ob[(size_t)(m0 + rloc) * 1024 + n0 + wc + 16 * jj + fr] = acc[i][jj][r] * iv;
            }
        return;
    }

    // finalize: 4 rows/block (one per wave), XCD-affine to y-quad; writes
    // only cols < tile_end (above-tile zeros written by prep).
    int s = bid - 512;                    // 0..2047; 512%8==0 so XCD = s&7
    int j = s & 7, i = s >> 3;
    int G = j >> 1, pband = j & 1;
    int idx2 = i * 2 + pband;             // 0..511
    int y  = ymem(G, idx2 >> 7);
    int rb = (idx2 >> 2) & 31;
    int b  = idx2 & 3;

    int tid = threadIdx.x;
    int wave = tid >> 6, lane = tid & 63;
    int q = y * 128 + rb * 4 + wave;
    int r = b * 2048 + q;
    int tile_end = (y + 1) * 128;
    float p = (lane < 16 && lane <= y) ? partials[(size_t)r * 16 + lane] : 0.f;
    p += __shfl_xor(p, 1, 64); p += __shfl_xor(p, 2, 64);
    p += __shfl_xor(p, 4, 64); p += __shfl_xor(p, 8, 64);
    float iv = 1.f / __shfl(p, 0, 64);
    const unsigned short* er = E + (size_t)r * 2048;
    float* wrow = W + (size_t)r * 2048;
#pragma unroll
    for (int cc = 0; cc < 4; ++cc) {
        int c0 = lane * 8 + cc * 512;
        if (c0 >= tile_end) continue;
        f32x4 o0 = {}, o1 = {};
        if (c0 <= q) {   // masked entries within a live chunk are exact bf16 zeros
            bf16x8 e = *(const bf16x8*)(er + c0);
#pragma unroll
            for (int jj = 0; jj < 4; ++jj) {
                o0[jj] = bf2f((unsigned short)e[jj]) * iv;
                o1[jj] = bf2f((unsigned short)e[jj + 4]) * iv;
            }
        }
        *((f32x4*)(wrow + c0)) = o0;
        *((f32x4*)(wrow + c0) + 1) = o1;
    }
}

// ---------------- launcher ----------------

extern "C" void kernel_launch(void* const* d_in, const int* in_sizes, int n_in,
                              void* d_out, int out_size, void* d_ws, size_t ws_size,
                              hipStream_t stream) {
    (void)in_sizes; (void)n_in; (void)out_size; (void)ws_size;
    const float* x  = (const float*)d_in[0];
    const float* Wq = (const float*)d_in[1];
    const float* Wk = (const float*)d_in[2];
    const float* Wv = (const float*)d_in[3];
    const int B = 4, T = 2048, D = 1024;
    const int M = B * T;  // 8192

    char* ws = (char*)d_ws;
    size_t off = 0;
    auto alloc = [&](size_t bytes) {
        void* p = ws + off; off += (bytes + 255) & ~(size_t)255; return p;
    };
    unsigned short* x_bf  = (unsigned short*)alloc((size_t)M * D * 2);
    unsigned short* Wqk_t = (unsigned short*)alloc((size_t)512 * D * 2);
    unsigned short* Wv_t  = (unsigned short*)alloc((size_t)D * D * 2);
    unsigned short* QK_bf = (unsigned short*)alloc((size_t)M * 512 * 2);
    unsigned short* Vt_bf = (unsigned short*)alloc((size_t)D * M * 2);
    unsigned short* E_bf  = (unsigned short*)alloc((size_t)M * T * 2);
    float*          parts = (float*)alloc((size_t)M * 16 * 4);

    float* outO = (float*)d_out;                       // [4][2048][1024]
    float* outW = (float*)d_out + (size_t)M * D;       // [4][2048][2048]

    // 1. prep: x->bf16 (grid-strided) + zero tiles + weight transposes
    prep<<<dim3(2048 + 480 + 256 + 256 + 1024), 256, 0, stream>>>(
        x, Wq, Wk, Wv, x_bf, Wqk_t, Wv_t, outW);

    // 2. QK GEMM + Vt GEMM, mod-3 interleaved (both run from t=0)
    gemm_qkvt<<<dim3(768), 256, 0, stream>>>(x_bf, Wqk_t, Wv_t, QK_bf, Vt_bf);

    // 3. scores -> bf16 E (unnormalized) + partial row sums (live tiles only)
    scores_e<<<dim3(544), 256, 0, stream>>>(QK_bf, E_bf, parts);

    // 4. PV GEMM (2D-XCD-tiled) + W finalize (live region only)
    pv_fin<<<dim3(512 + 2048), 256, 0, stream>>>(E_bf, Vt_bf, parts, outO, outW);
}